// Round 7
// baseline (384.344 us; speedup 1.0000x reference)
//
#include <hip/hip_runtime.h>

#define NN   8192
#define DIN  512
#define H1   32
#define H2   16
#define NE   262144
#define EPSV 1e-32f
#define NREP 8

// ---------------- k1: XW0 = X @ W0   [NN x H1] ----------------
__global__ __launch_bounds__(256) void k_xw0(const float* __restrict__ X,
                                             const float* __restrict__ W0,
                                             float* __restrict__ XW0) {
    int t = blockIdx.x * 256 + threadIdx.x;
    int r = t >> 5, c = t & 31;
    const float4* Xr = reinterpret_cast<const float4*>(X + (size_t)r * DIN);
    float acc = 0.f;
#pragma unroll 8
    for (int k4 = 0; k4 < DIN / 4; ++k4) {
        float4 x = Xr[k4];
        int k = k4 * 4;
        acc = fmaf(x.x, W0[(k + 0) * H1 + c], acc);
        acc = fmaf(x.y, W0[(k + 1) * H1 + c], acc);
        acc = fmaf(x.z, W0[(k + 2) * H1 + c], acc);
        acc = fmaf(x.w, W0[(k + 3) * H1 + c], acc);
    }
    XW0[t] = acc;
}

// ---------------- k2: hacc_r[rep] += scatter(edge_val * XW0[col]) ----------------
// 8-way replicated accumulator: per-64B-line atomic serialization 512 -> 64.
// rep = blockIdx&7; a line's ~512 updating edges are spread uniformly
// across blocks, hence across replicas.
__global__ __launch_bounds__(256) void k_spmm1(const int* __restrict__ er,
                                               const int* __restrict__ ec,
                                               const float* __restrict__ ev,
                                               const float* __restrict__ XW0,
                                               float* __restrict__ hacc_r) {
    int t = blockIdx.x * 256 + threadIdx.x;
    int e = t >> 5, c = t & 31;
    int rep = blockIdx.x & (NREP - 1);
    int row = er[e], col = ec[e];
    float v = ev[e];
    atomicAdd(&hacc_r[(size_t)rep * (NN * H1) + row * H1 + c],
              v * XW0[col * H1 + c]);
}

// ---------------- k3: HW1 = relu(sum_rep hacc_r) @ W1   [NN x H2] ----------------
__global__ __launch_bounds__(256) void k_hw1(const float* __restrict__ hacc_r,
                                             const float* __restrict__ W1,
                                             float* __restrict__ HW1) {
    int t = blockIdx.x * 256 + threadIdx.x;
    int r = t >> 4, c = t & 15;
    float acc = 0.f;
#pragma unroll
    for (int k = 0; k < H1; ++k) {
        float s = 0.f;
#pragma unroll
        for (int rep = 0; rep < NREP; ++rep)
            s += hacc_r[(size_t)rep * (NN * H1) + r * H1 + k];
        acc = fmaf(fmaxf(s, 0.f), W1[k * H2 + c], acc);
    }
    HW1[t] = acc;
}

// ---------------- k4: mean_r[rep] += scatter(edge_val * HW1[col]) ----------------
__global__ __launch_bounds__(256) void k_spmm2(const int* __restrict__ er,
                                               const int* __restrict__ ec,
                                               const float* __restrict__ ev,
                                               const float* __restrict__ HW1,
                                               float* __restrict__ mean_r) {
    int t = blockIdx.x * 256 + threadIdx.x;
    int e = t >> 4, c = t & 15;
    int rep = blockIdx.x & (NREP - 1);
    int row = er[e], col = ec[e];
    float v = ev[e];
    atomicAdd(&mean_r[(size_t)rep * (NN * H2) + row * H2 + c],
              v * HW1[col * H2 + c]);
}

// ---------------- k4b: mean = sum_rep mean_r  (coalesced, ~1 us) ----------------
__global__ __launch_bounds__(256) void k_redm(const float* __restrict__ mean_r,
                                              float* __restrict__ mean) {
    int t = blockIdx.x * 256 + threadIdx.x;   // 0 .. NN*H2-1
    float s = 0.f;
#pragma unroll
    for (int rep = 0; rep < NREP; ++rep)
        s += mean_r[(size_t)rep * (NN * H2) + t];
    mean[t] = s;
}

// ---------------- k5: out = sigmoid(Z @ Z^T), Z = max(mean, EPS) ----------------
// (byte-identical to round 6 — proven store path + conflict-free zj layout)
#define TI 128

__device__ __forceinline__ float sigm(float x) {
    return __fdividef(1.0f, 1.0f + __expf(-x));
}

__global__ __launch_bounds__(256) void k_decode(const float* __restrict__ Zm,
                                                float* __restrict__ out) {
    __shared__ float zi[TI * 16];    // pitch 16, granule-XOR
    __shared__ float zj[TI * 32];    // pitch 32, 8-slot XOR placement
    const int i0 = blockIdx.y * TI, j0 = blockIdx.x * TI;
    const int tid = threadIdx.x;

#pragma unroll
    for (int l = 0; l < 2; ++l) {
        int t = tid + l * 256;          // 0..511
        int r = t >> 2, q = t & 3;      // row, float4-granule
        float4 a = *reinterpret_cast<const float4*>(Zm + (size_t)(i0 + r) * H2 + q * 4);
        float4 b = *reinterpret_cast<const float4*>(Zm + (size_t)(j0 + r) * H2 + q * 4);
        a.x = fmaxf(a.x, EPSV); a.y = fmaxf(a.y, EPSV);
        a.z = fmaxf(a.z, EPSV); a.w = fmaxf(a.w, EPSV);
        b.x = fmaxf(b.x, EPSV); b.y = fmaxf(b.y, EPSV);
        b.z = fmaxf(b.z, EPSV); b.w = fmaxf(b.w, EPSV);
        int g  = (r >> 3);              // 0..15
        int qs = q ^ (g & 3);                       // zi granule swizzle
        int p  = (q ^ (g & 3)) | (g & 4);           // zj slot placement
        *reinterpret_cast<float4*>(&zi[r * 16 + qs * 4]) = a;
        *reinterpret_cast<float4*>(&zj[r * 32 + p  * 4]) = b;
    }
    __syncthreads();

    const int tx = tid & 15, ty = tid >> 4;
    float acc[8][8] = {};
#pragma unroll
    for (int k4 = 0; k4 < 4; ++k4) {
        float4 ra[8], rb[8];
        const int qi = (k4 ^ (ty & 3)) * 4;              // zi un-swizzle (r>>3 == ty)
        const int pj = ((k4 ^ (tx & 3)) | (tx & 4)) * 4; // zj slot (r>>3 == tx)
#pragma unroll
        for (int a = 0; a < 8; ++a)
            ra[a] = *reinterpret_cast<const float4*>(&zi[(ty * 8 + a) * 16 + qi]);
#pragma unroll
        for (int b = 0; b < 8; ++b)
            rb[b] = *reinterpret_cast<const float4*>(&zj[(tx * 8 + b) * 32 + pj]);
#pragma unroll
        for (int a = 0; a < 8; ++a)
#pragma unroll
            for (int b = 0; b < 8; ++b) {
                acc[a][b] = fmaf(ra[a].x, rb[b].x, acc[a][b]);
                acc[a][b] = fmaf(ra[a].y, rb[b].y, acc[a][b]);
                acc[a][b] = fmaf(ra[a].z, rb[b].z, acc[a][b]);
                acc[a][b] = fmaf(ra[a].w, rb[b].w, acc[a][b]);
            }
    }

#pragma unroll
    for (int a = 0; a < 8; ++a) {
        size_t rowbase = (size_t)(i0 + ty * 8 + a) * NN + j0 + tx * 8;
#pragma unroll
        for (int b4 = 0; b4 < 8; b4 += 4) {
            float4 o;
            o.x = sigm(acc[a][b4 + 0]);
            o.y = sigm(acc[a][b4 + 1]);
            o.z = sigm(acc[a][b4 + 2]);
            o.w = sigm(acc[a][b4 + 3]);
            *reinterpret_cast<float4*>(out + rowbase + b4) = o;
        }
    }
}

extern "C" void kernel_launch(void* const* d_in, const int* in_sizes, int n_in,
                              void* d_out, int out_size, void* d_ws, size_t ws_size,
                              hipStream_t stream) {
    const float* X  = (const float*)d_in[0];
    const int*   er = (const int*)d_in[1];
    const int*   ec = (const int*)d_in[2];
    const float* ev = (const float*)d_in[3];
    const float* W0 = (const float*)d_in[4];
    const float* W1 = (const float*)d_in[5];
    // d_in[6] = W2: dead in eval path.
    float* out = (float*)d_out;

    char* ws = (char*)d_ws;
    float* XW0    = (float*)(ws);                            // 1 MB
    float* hacc_r = (float*)(ws + (1 << 20));                // 8 MB  (8 x 1 MB)
    float* mean_r = (float*)(ws + (9 << 20));                // 4 MB  (8 x 512 KB)
    float* mean   = (float*)(ws + (13 << 20));               // 512 KB
    float* HW1    = (float*)(ws + (13 << 20) + (512 << 10)); // 512 KB

    // zero the replicated accumulators (contiguous 12 MB)
    hipMemsetAsync(hacc_r, 0, 12 << 20, stream);

    k_xw0   <<<NN * H1 / 256, 256, 0, stream>>>(X, W0, XW0);
    k_spmm1 <<<NE * H1 / 256, 256, 0, stream>>>(er, ec, ev, XW0, hacc_r);
    k_hw1   <<<NN * H2 / 256, 256, 0, stream>>>(hacc_r, W1, HW1);
    k_spmm2 <<<NE * H2 / 256, 256, 0, stream>>>(er, ec, ev, HW1, mean_r);
    k_redm  <<<NN * H2 / 256, 256, 0, stream>>>(mean_r, mean);
    k_decode<<<dim3(NN / TI, NN / TI), 256, 0, stream>>>(mean, out);
}

// Round 8
// 383.838 us; speedup vs baseline: 1.0013x; 1.0013x over previous
//
#include <hip/hip_runtime.h>

#define NN   8192
#define DIN  512
#define H1   32
#define H2   16
#define NE   262144
#define EPSV 1e-32f

// ---------------- k1: XW0 = X @ W0   [NN x H1] ----------------
__global__ __launch_bounds__(256) void k_xw0(const float* __restrict__ X,
                                             const float* __restrict__ W0,
                                             float* __restrict__ XW0) {
    int t = blockIdx.x * 256 + threadIdx.x;
    int r = t >> 5, c = t & 31;
    const float4* Xr = reinterpret_cast<const float4*>(X + (size_t)r * DIN);
    float acc = 0.f;
#pragma unroll 8
    for (int k4 = 0; k4 < DIN / 4; ++k4) {
        float4 x = Xr[k4];
        int k = k4 * 4;
        acc = fmaf(x.x, W0[(k + 0) * H1 + c], acc);
        acc = fmaf(x.y, W0[(k + 1) * H1 + c], acc);
        acc = fmaf(x.z, W0[(k + 2) * H1 + c], acc);
        acc = fmaf(x.w, W0[(k + 3) * H1 + c], acc);
    }
    XW0[t] = acc;
}

// ---------------- CSR build: histogram -> scan -> scatter (verified R2) ----------------
__global__ __launch_bounds__(256) void k_hist(const int* __restrict__ er,
                                              int* __restrict__ cnt) {
    int e = blockIdx.x * 256 + threadIdx.x;
    atomicAdd(&cnt[er[e]], 1);
}

__global__ __launch_bounds__(1024) void k_scan(const int* __restrict__ cnt,
                                               int* __restrict__ rptr,
                                               int* __restrict__ rfill) {
    __shared__ int part[1024];
    int tid = threadIdx.x;
    int local[8];
    int s = 0;
#pragma unroll
    for (int i = 0; i < 8; ++i) { local[i] = s; s += cnt[tid * 8 + i]; }
    part[tid] = s;
    __syncthreads();
    for (int off = 1; off < 1024; off <<= 1) {
        int v = (tid >= off) ? part[tid - off] : 0;
        __syncthreads();
        part[tid] += v;
        __syncthreads();
    }
    int base = (tid == 0) ? 0 : part[tid - 1];
#pragma unroll
    for (int i = 0; i < 8; ++i) {
        rptr[tid * 8 + i]  = base + local[i];
        rfill[tid * 8 + i] = base + local[i];
    }
    if (tid == 1023) rptr[8192] = part[1023];
}

__global__ __launch_bounds__(256) void k_scatter(const int* __restrict__ er,
                                                 const int* __restrict__ ec,
                                                 const float* __restrict__ ev,
                                                 int* __restrict__ rfill,
                                                 int* __restrict__ ccol,
                                                 float* __restrict__ cval) {
    int e = blockIdx.x * 256 + threadIdx.x;
    int p = atomicAdd(&rfill[er[e]], 1);
    ccol[p] = ec[e];
    cval[p] = ev[e];
}

// ---------------- k2: hacc[r,:] = sum_p cval[p] * XW0[ccol[p],:]  ----------------
// One block per row. 8 edge-groups x 32 feature lanes: 8 independent 128B
// gathers in flight per iteration (avg deg 32 -> ~4 iterations), no serial
// chain, no atomics. LDS tree reduce 8 -> 1.
__global__ __launch_bounds__(256) void k_gath1(const int* __restrict__ rptr,
                                               const int* __restrict__ ccol,
                                               const float* __restrict__ cval,
                                               const float* __restrict__ XW0,
                                               float* __restrict__ hacc) {
    __shared__ float sh[256];
    int r = blockIdx.x;
    int c = threadIdx.x & 31, g = threadIdx.x >> 5;
    int start = rptr[r], end = rptr[r + 1];
    float part = 0.f;
    for (int p = start + g; p < end; p += 8)
        part = fmaf(cval[p], XW0[ccol[p] * H1 + c], part);
    sh[threadIdx.x] = part;          // bank c, 2-way across wave halves: free
    __syncthreads();
    if (threadIdx.x < 32) {
        float s = sh[c];
#pragma unroll
        for (int gg = 1; gg < 8; ++gg) s += sh[gg * 32 + c];
        hacc[r * H1 + c] = s;
    }
}

// ---------------- k3: HW1 = relu(hacc) @ W1   [NN x H2] (unchanged R6) ----------------
__global__ __launch_bounds__(256) void k_hw1(const float* __restrict__ hacc,
                                             const float* __restrict__ W1,
                                             float* __restrict__ HW1) {
    int t = blockIdx.x * 256 + threadIdx.x;
    int r = t >> 4, c = t & 15;
    const float* hr = hacc + r * H1;
    float acc = 0.f;
#pragma unroll
    for (int k = 0; k < H1; ++k)
        acc = fmaf(fmaxf(hr[k], 0.f), W1[k * H2 + c], acc);
    HW1[t] = acc;
}

// ---------------- k4: mean[r,:] = sum_p cval[p] * HW1[ccol[p],:] ----------------
// 16 edge-groups x 16 feature lanes: 16 independent 64B gathers in flight.
__global__ __launch_bounds__(256) void k_gath2(const int* __restrict__ rptr,
                                               const int* __restrict__ ccol,
                                               const float* __restrict__ cval,
                                               const float* __restrict__ HW1,
                                               float* __restrict__ mean) {
    __shared__ float sh[256];
    int r = blockIdx.x;
    int c = threadIdx.x & 15, g = threadIdx.x >> 4;
    int start = rptr[r], end = rptr[r + 1];
    float part = 0.f;
    for (int p = start + g; p < end; p += 16)
        part = fmaf(cval[p], HW1[ccol[p] * H2 + c], part);
    sh[threadIdx.x] = part;
    __syncthreads();
    if (threadIdx.x < 16) {
        float s = sh[c];
#pragma unroll
        for (int gg = 1; gg < 16; ++gg) s += sh[gg * 16 + c];
        mean[r * H2 + c] = s;
    }
}

// ---------------- k5: out = sigmoid(Z @ Z^T), Z = max(mean, EPS) ----------------
// (byte-identical to round 6 — proven store path + conflict-free zj layout)
#define TI 128

__device__ __forceinline__ float sigm(float x) {
    return __fdividef(1.0f, 1.0f + __expf(-x));
}

__global__ __launch_bounds__(256) void k_decode(const float* __restrict__ Zm,
                                                float* __restrict__ out) {
    __shared__ float zi[TI * 16];    // pitch 16, granule-XOR
    __shared__ float zj[TI * 32];    // pitch 32, 8-slot XOR placement
    const int i0 = blockIdx.y * TI, j0 = blockIdx.x * TI;
    const int tid = threadIdx.x;

#pragma unroll
    for (int l = 0; l < 2; ++l) {
        int t = tid + l * 256;          // 0..511
        int r = t >> 2, q = t & 3;      // row, float4-granule
        float4 a = *reinterpret_cast<const float4*>(Zm + (size_t)(i0 + r) * H2 + q * 4);
        float4 b = *reinterpret_cast<const float4*>(Zm + (size_t)(j0 + r) * H2 + q * 4);
        a.x = fmaxf(a.x, EPSV); a.y = fmaxf(a.y, EPSV);
        a.z = fmaxf(a.z, EPSV); a.w = fmaxf(a.w, EPSV);
        b.x = fmaxf(b.x, EPSV); b.y = fmaxf(b.y, EPSV);
        b.z = fmaxf(b.z, EPSV); b.w = fmaxf(b.w, EPSV);
        int g  = (r >> 3);              // 0..15
        int qs = q ^ (g & 3);                       // zi granule swizzle
        int p  = (q ^ (g & 3)) | (g & 4);           // zj slot placement
        *reinterpret_cast<float4*>(&zi[r * 16 + qs * 4]) = a;
        *reinterpret_cast<float4*>(&zj[r * 32 + p  * 4]) = b;
    }
    __syncthreads();

    const int tx = tid & 15, ty = tid >> 4;
    float acc[8][8] = {};
#pragma unroll
    for (int k4 = 0; k4 < 4; ++k4) {
        float4 ra[8], rb[8];
        const int qi = (k4 ^ (ty & 3)) * 4;              // zi un-swizzle (r>>3 == ty)
        const int pj = ((k4 ^ (tx & 3)) | (tx & 4)) * 4; // zj slot (r>>3 == tx)
#pragma unroll
        for (int a = 0; a < 8; ++a)
            ra[a] = *reinterpret_cast<const float4*>(&zi[(ty * 8 + a) * 16 + qi]);
#pragma unroll
        for (int b = 0; b < 8; ++b)
            rb[b] = *reinterpret_cast<const float4*>(&zj[(tx * 8 + b) * 32 + pj]);
#pragma unroll
        for (int a = 0; a < 8; ++a)
#pragma unroll
            for (int b = 0; b < 8; ++b) {
                acc[a][b] = fmaf(ra[a].x, rb[b].x, acc[a][b]);
                acc[a][b] = fmaf(ra[a].y, rb[b].y, acc[a][b]);
                acc[a][b] = fmaf(ra[a].z, rb[b].z, acc[a][b]);
                acc[a][b] = fmaf(ra[a].w, rb[b].w, acc[a][b]);
            }
    }

#pragma unroll
    for (int a = 0; a < 8; ++a) {
        size_t rowbase = (size_t)(i0 + ty * 8 + a) * NN + j0 + tx * 8;
#pragma unroll
        for (int b4 = 0; b4 < 8; b4 += 4) {
            float4 o;
            o.x = sigm(acc[a][b4 + 0]);
            o.y = sigm(acc[a][b4 + 1]);
            o.z = sigm(acc[a][b4 + 2]);
            o.w = sigm(acc[a][b4 + 3]);
            *reinterpret_cast<float4*>(out + rowbase + b4) = o;
        }
    }
}

extern "C" void kernel_launch(void* const* d_in, const int* in_sizes, int n_in,
                              void* d_out, int out_size, void* d_ws, size_t ws_size,
                              hipStream_t stream) {
    const float* X  = (const float*)d_in[0];
    const int*   er = (const int*)d_in[1];
    const int*   ec = (const int*)d_in[2];
    const float* ev = (const float*)d_in[3];
    const float* W0 = (const float*)d_in[4];
    const float* W1 = (const float*)d_in[5];
    // d_in[6] = W2: dead in eval path.
    float* out = (float*)d_out;

    char* ws = (char*)d_ws;
    float* XW0  = (float*)(ws);                          // 1 MB
    float* hacc = (float*)(ws + (1 << 20));              // 1 MB
    float* mean = (float*)(ws + (2 << 20));              // 512 KB
    float* HW1  = (float*)(ws + (2 << 20) + (512 << 10));// 512 KB
    int*   cnt  = (int*)  (ws + (3 << 20));              // 32 KB
    int*   rptr = (int*)  (ws + (3 << 20) + (64 << 10)); // 8193 ints
    int*   rfill= (int*)  (ws + (3 << 20) + (128 << 10));// 32 KB
    int*   ccol = (int*)  (ws + (3 << 20) + (192 << 10));// 1 MB
    float* cval = (float*)(ws + (4 << 20) + (192 << 10));// 1 MB

    hipMemsetAsync(cnt, 0, 32 << 10, stream);            // histogram zero-init

    k_xw0    <<<NN * H1 / 256, 256, 0, stream>>>(X, W0, XW0);
    k_hist   <<<NE / 256, 256, 0, stream>>>(er, cnt);
    k_scan   <<<1, 1024, 0, stream>>>(cnt, rptr, rfill);
    k_scatter<<<NE / 256, 256, 0, stream>>>(er, ec, ev, rfill, ccol, cval);
    k_gath1  <<<NN, 256, 0, stream>>>(rptr, ccol, cval, XW0, hacc);
    k_hw1    <<<NN * H2 / 256, 256, 0, stream>>>(hacc, W1, HW1);
    k_gath2  <<<NN, 256, 0, stream>>>(rptr, ccol, cval, HW1, mean);
    k_decode <<<dim3(NN / TI, NN / TI), 256, 0, stream>>>(mean, out);
}

// Round 9
// 374.760 us; speedup vs baseline: 1.0256x; 1.0242x over previous
//
#include <hip/hip_runtime.h>

#define NN   8192
#define DIN  512
#define H1   32
#define H2   16
#define NE   262144
#define EPSV 1e-32f

// ---------------- k1: XW0 = X @ W0  [NN x H1]; also zero-inits hacc & mean ----------------
// 1024 blocks x 256 = 262144 threads == NN*H1 exactly; first NN*H2 threads
// also zero mean. Replaces the hipMemsetAsync dispatch (harness re-poisons
// d_ws to 0xAA before every timed launch, so init must happen every call).
__global__ __launch_bounds__(256) void k_xw0(const float* __restrict__ X,
                                             const float* __restrict__ W0,
                                             float* __restrict__ XW0,
                                             float* __restrict__ hacc,
                                             float* __restrict__ mean) {
    int t = blockIdx.x * 256 + threadIdx.x;
    hacc[t] = 0.f;
    if (t < NN * H2) mean[t] = 0.f;
    int r = t >> 5, c = t & 31;
    const float4* Xr = reinterpret_cast<const float4*>(X + (size_t)r * DIN);
    float acc = 0.f;
#pragma unroll 8
    for (int k4 = 0; k4 < DIN / 4; ++k4) {
        float4 x = Xr[k4];
        int k = k4 * 4;
        acc = fmaf(x.x, W0[(k + 0) * H1 + c], acc);
        acc = fmaf(x.y, W0[(k + 1) * H1 + c], acc);
        acc = fmaf(x.z, W0[(k + 2) * H1 + c], acc);
        acc = fmaf(x.w, W0[(k + 3) * H1 + c], acc);
    }
    XW0[t] = acc;
}

// ---------------- k2: hacc += scatter(edge_val * XW0[col])  (grid-stride) ----------------
// 2048 blocks, 16 iterations/thread (G11): same 8.4M atomics, fewer waves to
// ramp. 32 lanes per edge; XW0 row reads 128B contiguous, L2-resident.
#define SPMM_GRID 2048
__global__ __launch_bounds__(256) void k_spmm1(const int* __restrict__ er,
                                               const int* __restrict__ ec,
                                               const float* __restrict__ ev,
                                               const float* __restrict__ XW0,
                                               float* __restrict__ hacc) {
    const int stride = SPMM_GRID * 256;
    for (int idx = blockIdx.x * 256 + threadIdx.x; idx < NE * H1; idx += stride) {
        int e = idx >> 5, c = idx & 31;
        atomicAdd(&hacc[er[e] * H1 + c], ev[e] * XW0[ec[e] * H1 + c]);
    }
}

// ---------------- k3: HW1 = relu(hacc) @ W1   [NN x H2] ----------------
__global__ __launch_bounds__(256) void k_hw1(const float* __restrict__ hacc,
                                             const float* __restrict__ W1,
                                             float* __restrict__ HW1) {
    int t = blockIdx.x * 256 + threadIdx.x;
    int r = t >> 4, c = t & 15;
    const float4* hr = reinterpret_cast<const float4*>(hacc + r * H1);
    float acc = 0.f;
#pragma unroll
    for (int k4 = 0; k4 < H1 / 4; ++k4) {
        float4 h = hr[k4];
        int k = k4 * 4;
        acc = fmaf(fmaxf(h.x, 0.f), W1[(k + 0) * H2 + c], acc);
        acc = fmaf(fmaxf(h.y, 0.f), W1[(k + 1) * H2 + c], acc);
        acc = fmaf(fmaxf(h.z, 0.f), W1[(k + 2) * H2 + c], acc);
        acc = fmaf(fmaxf(h.w, 0.f), W1[(k + 3) * H2 + c], acc);
    }
    HW1[t] = acc;
}

// ---------------- k4: mean += scatter(edge_val * HW1[col])  (grid-stride) ----------------
__global__ __launch_bounds__(256) void k_spmm2(const int* __restrict__ er,
                                               const int* __restrict__ ec,
                                               const float* __restrict__ ev,
                                               const float* __restrict__ HW1,
                                               float* __restrict__ mean) {
    const int stride = SPMM_GRID * 256;
    for (int idx = blockIdx.x * 256 + threadIdx.x; idx < NE * H2; idx += stride) {
        int e = idx >> 4, c = idx & 15;
        atomicAdd(&mean[er[e] * H2 + c], ev[e] * HW1[ec[e] * H2 + c]);
    }
}

// ---------------- k5: out = sigmoid(Z @ Z^T), Z = max(mean, EPS) ----------------
// (byte-identical to round 6 — proven store path + conflict-free zj layout)
#define TI 128

__device__ __forceinline__ float sigm(float x) {
    return __fdividef(1.0f, 1.0f + __expf(-x));
}

__global__ __launch_bounds__(256) void k_decode(const float* __restrict__ Zm,
                                                float* __restrict__ out) {
    __shared__ float zi[TI * 16];    // pitch 16, granule-XOR
    __shared__ float zj[TI * 32];    // pitch 32, 8-slot XOR placement
    const int i0 = blockIdx.y * TI, j0 = blockIdx.x * TI;
    const int tid = threadIdx.x;

#pragma unroll
    for (int l = 0; l < 2; ++l) {
        int t = tid + l * 256;          // 0..511
        int r = t >> 2, q = t & 3;      // row, float4-granule
        float4 a = *reinterpret_cast<const float4*>(Zm + (size_t)(i0 + r) * H2 + q * 4);
        float4 b = *reinterpret_cast<const float4*>(Zm + (size_t)(j0 + r) * H2 + q * 4);
        a.x = fmaxf(a.x, EPSV); a.y = fmaxf(a.y, EPSV);
        a.z = fmaxf(a.z, EPSV); a.w = fmaxf(a.w, EPSV);
        b.x = fmaxf(b.x, EPSV); b.y = fmaxf(b.y, EPSV);
        b.z = fmaxf(b.z, EPSV); b.w = fmaxf(b.w, EPSV);
        int g  = (r >> 3);              // 0..15
        int qs = q ^ (g & 3);                       // zi granule swizzle
        int p  = (q ^ (g & 3)) | (g & 4);           // zj slot placement
        *reinterpret_cast<float4*>(&zi[r * 16 + qs * 4]) = a;
        *reinterpret_cast<float4*>(&zj[r * 32 + p  * 4]) = b;
    }
    __syncthreads();

    const int tx = tid & 15, ty = tid >> 4;
    float acc[8][8] = {};
#pragma unroll
    for (int k4 = 0; k4 < 4; ++k4) {
        float4 ra[8], rb[8];
        const int qi = (k4 ^ (ty & 3)) * 4;              // zi un-swizzle (r>>3 == ty)
        const int pj = ((k4 ^ (tx & 3)) | (tx & 4)) * 4; // zj slot (r>>3 == tx)
#pragma unroll
        for (int a = 0; a < 8; ++a)
            ra[a] = *reinterpret_cast<const float4*>(&zi[(ty * 8 + a) * 16 + qi]);
#pragma unroll
        for (int b = 0; b < 8; ++b)
            rb[b] = *reinterpret_cast<const float4*>(&zj[(tx * 8 + b) * 32 + pj]);
#pragma unroll
        for (int a = 0; a < 8; ++a)
#pragma unroll
            for (int b = 0; b < 8; ++b) {
                acc[a][b] = fmaf(ra[a].x, rb[b].x, acc[a][b]);
                acc[a][b] = fmaf(ra[a].y, rb[b].y, acc[a][b]);
                acc[a][b] = fmaf(ra[a].z, rb[b].z, acc[a][b]);
                acc[a][b] = fmaf(ra[a].w, rb[b].w, acc[a][b]);
            }
    }

#pragma unroll
    for (int a = 0; a < 8; ++a) {
        size_t rowbase = (size_t)(i0 + ty * 8 + a) * NN + j0 + tx * 8;
#pragma unroll
        for (int b4 = 0; b4 < 8; b4 += 4) {
            float4 o;
            o.x = sigm(acc[a][b4 + 0]);
            o.y = sigm(acc[a][b4 + 1]);
            o.z = sigm(acc[a][b4 + 2]);
            o.w = sigm(acc[a][b4 + 3]);
            *reinterpret_cast<float4*>(out + rowbase + b4) = o;
        }
    }
}

extern "C" void kernel_launch(void* const* d_in, const int* in_sizes, int n_in,
                              void* d_out, int out_size, void* d_ws, size_t ws_size,
                              hipStream_t stream) {
    const float* X  = (const float*)d_in[0];
    const int*   er = (const int*)d_in[1];
    const int*   ec = (const int*)d_in[2];
    const float* ev = (const float*)d_in[3];
    const float* W0 = (const float*)d_in[4];
    const float* W1 = (const float*)d_in[5];
    // d_in[6] = W2: dead in eval path.
    float* out = (float*)d_out;

    char* ws = (char*)d_ws;
    float* XW0  = (float*)(ws);                          // 1 MB
    float* hacc = (float*)(ws + (1 << 20));              // 1 MB
    float* mean = (float*)(ws + (2 << 20));              // 512 KB
    float* HW1  = (float*)(ws + (2 << 20) + (512 << 10));// 512 KB

    k_xw0   <<<NN * H1 / 256, 256, 0, stream>>>(X, W0, XW0, hacc, mean);
    k_spmm1 <<<SPMM_GRID, 256, 0, stream>>>(er, ec, ev, XW0, hacc);
    k_hw1   <<<NN * H2 / 256, 256, 0, stream>>>(hacc, W1, HW1);
    k_spmm2 <<<SPMM_GRID, 256, 0, stream>>>(er, ec, ev, HW1, mean);
    k_decode<<<dim3(NN / TI, NN / TI), 256, 0, stream>>>(mean, out);
}